// Round 18
// baseline (766.100 us; speedup 1.0000x reference)
//
#include <hip/hip_runtime.h>
#include <hip/hip_bf16.h>
#include <cstdint>

#define DEV_INLINE __device__ __forceinline__

typedef unsigned short u16;
typedef unsigned int   u32;
typedef short bf16x8 __attribute__((ext_vector_type(8)));
typedef float f32x4  __attribute__((ext_vector_type(4)));

#define AS_GLOBAL(p) ((const __attribute__((address_space(1))) void*)(p))
#define AS_LDS(p)    ((__attribute__((address_space(3))) void*)(p))

constexpr int NP = 120000, NB = 8, NM = 60000, KNN = 16;
constexpr int NE = NM * KNN;          // 960000
constexpr float EPS = 1e-5f;

constexpr size_t O_POS   = (size_t)NM * 128;
constexpr size_t O_BATCH = O_POS + (size_t)NM * 3;
constexpr size_t O_REFL  = O_BATCH + NM;
constexpr size_t O_SF    = O_REFL + NM;

// ---------------- device-global buffers -------------------------------------
__device__ float  g_pos_s[(size_t)NP * 4];
__device__ u16    g_xbf[(size_t)NP * 32];         // x in bf16
__device__ u16    g_pre2[(size_t)NE * 64];        // fragment-tile layout
__device__ u32    g_mm[(size_t)NM * 128];         // packed bf16 {lo=max, hi=min}
__device__ float  g_agg[(size_t)NM * 128];        // f32 residual
__device__ u16    g_aggbf[(size_t)NM * 128];      // bf16 GEMM input
__device__ u16    g_bufA[(size_t)NM * 512];
__device__ u16    g_bufB[(size_t)NM * 512];
__device__ float  g_obuf[(size_t)NM * 128];
__device__ float  g_sum[512], g_sqs[512];
__device__ float  g_cfa[512],  g_cfb[512];    // bank 1
__device__ float  g_cfa2[512], g_cfb2[512];   // bank 2
__device__ float  g_cfa3[512], g_cfb3[512];   // bank 3
__device__ float  g_b3adj[128], g_pbadj[128];
// transposed bf16 weights [N][K]
__device__ u16 g_w1t[64 * 64];      // K padded 36->64 (zeros)
__device__ u16 g_w2t[64 * 64];
__device__ u16 g_w3t[128 * 64];     // bn2-folded in place per launch
__device__ u16 g_expwt[512 * 128];
__device__ u16 g_pw0t[512 * 512];
__device__ u16 g_pw1t[512 * 512];
__device__ u16 g_projwt[128 * 512]; // c1-bn-folded in place per launch

template<int ID> DEV_INLINE const u16* ubufsel() {
  if constexpr (ID == 1) return g_aggbf;
  else if constexpr (ID == 2) return g_bufA;
  else return g_bufB;
}
template<int ID> DEV_INLINE u16* obufsel() {
  if constexpr (ID == 2) return g_bufA;
  else return g_bufB;
}
template<int ID> DEV_INLINE const u16* wsel() {
  if constexpr (ID == 3) return g_expwt;
  else if constexpr (ID == 4) return g_pw0t;
  else if constexpr (ID == 5) return g_pw1t;
  else return g_projwt;
}
template<int BK> DEV_INLINE float* cfaP() {
  if constexpr (BK == 1) return g_cfa; else if constexpr (BK == 2) return g_cfa2; else return g_cfa3;
}
template<int BK> DEV_INLINE float* cfbP() {
  if constexpr (BK == 1) return g_cfb; else if constexpr (BK == 2) return g_cfb2; else return g_cfb3;
}

// ---------------- helpers ----------------------------------------------------
DEV_INLINE float bf2f(u16 u) { u32 x = (u32)u << 16; float f; __builtin_memcpy(&f, &x, 4); return f; }
DEV_INLINE u16 f2bf(float f) {
  u32 x; __builtin_memcpy(&x, &f, 4);
  return (u16)((x + 0x7FFFu + ((x >> 16) & 1u)) >> 16);
}
DEV_INLINE u32 pack2(float a, float b) { return (u32)f2bf(a) | ((u32)f2bf(b) << 16); }

// ---------------- tiny kernels ----------------------------------------------
__global__ void prep_pos_x(const float* __restrict__ pos, const int* __restrict__ batch,
                           const float* __restrict__ refl, const float* __restrict__ sf,
                           const float* __restrict__ x) {
  int i = blockIdx.x * blockDim.x + threadIdx.x;
  if (i >= NP) return;
  float s = sf[batch[i]];
  float4 v;
  v.x = pos[(size_t)i*3+0] / s;
  v.y = pos[(size_t)i*3+1] / s;
  v.z = pos[(size_t)i*3+2] / s;
  v.w = refl[i];   // gate == 1 exactly
  *reinterpret_cast<float4*>(g_pos_s + (size_t)i*4) = v;
  const float4* xr = reinterpret_cast<const float4*>(x + (size_t)i*32);
#pragma unroll
  for (int q = 0; q < 4; q++) {
    float4 a = xr[q*2], b = xr[q*2+1];
    uint4 u = make_uint4(pack2(a.x,a.y), pack2(a.z,a.w), pack2(b.x,b.y), pack2(b.z,b.w));
    *reinterpret_cast<uint4*>(g_xbf + (size_t)i*32 + q*8) = u;
  }
}

__global__ void tail_out(const float* __restrict__ pos, const int* __restrict__ batch,
                         const float* __restrict__ refl, const float* __restrict__ sf,
                         const int* __restrict__ idx, float* __restrict__ out) {
  int i = blockIdx.x * blockDim.x + threadIdx.x;
  if (i < NM) {
    int p = idx[i];
    out[O_POS + (size_t)i*3+0] = pos[(size_t)p*3+0];
    out[O_POS + (size_t)i*3+1] = pos[(size_t)p*3+1];
    out[O_POS + (size_t)i*3+2] = pos[(size_t)p*3+2];
    out[O_BATCH + i] = (float)batch[p];
    out[O_REFL  + i] = refl[p];
  }
  if (i < NB) out[O_SF + i] = sf[i];
}

__global__ void zero_stats() {
  int t = threadIdx.x;
  g_sum[t] = 0.f; g_sqs[t] = 0.f;
}

// transpose + bf16-convert all weights (one kernel)
__global__ void prep_weights(const float* __restrict__ W1, const float* __restrict__ W2,
                             const float* __restrict__ W3, const float* __restrict__ expW,
                             const float* __restrict__ pwW, const float* __restrict__ projW) {
  int i = blockIdx.x * 256 + threadIdx.x;
  const int s0 = 4096, s1 = 4096, s2 = 8192, s3 = 65536, s4 = 262144, s5 = 262144, s6 = 65536;
  if (i < s0) { int n = i >> 6, k = i & 63; g_w1t[i] = (k < 36) ? f2bf(W1[k*64 + n]) : (u16)0; return; }
  i -= s0;
  if (i < s1) { int n = i >> 6, k = i & 63; g_w2t[i] = f2bf(W2[k*64 + n]); return; }
  i -= s1;
  if (i < s2) { int n = i >> 6, k = i & 63; g_w3t[i] = f2bf(W3[k*128 + n]); return; }
  i -= s2;
  if (i < s3) { int n = i >> 7, k = i & 127; g_expwt[i] = f2bf(expW[k*512 + n]); return; }
  i -= s3;
  if (i < s4) { int n = i >> 9, k = i & 511; g_pw0t[i] = f2bf(pwW[k*512 + n]); return; }
  i -= s4;
  if (i < s5) { int n = i >> 9, k = i & 511; g_pw1t[i] = f2bf(pwW[262144 + k*512 + n]); return; }
  i -= s5;
  if (i < s6) { int n = i >> 9, k = i & 511; g_projwt[i] = f2bf(projW[k*128 + n]); return; }
}

// param: BN params -> bank BK from stats in g_sum/g_sqs; then zero stats
template<int BK>
__global__ void param_bn(const float* __restrict__ g, const float* __restrict__ be,
                         float n, int C) {
  int c = threadIdx.x;
  if (c < C) {
    float mean = g_sum[c] / n;
    float var  = fmaxf(g_sqs[c] / n - mean * mean, 0.f);
    float a = g[c] * rsqrtf(var + EPS);
    cfaP<BK>()[c] = a;
    cfbP<BK>()[c] = be[c] - a * mean;
  }
  __syncthreads();
  g_sum[c] = 0.f; g_sqs[c] = 0.f;
}

// BN of u = w*h + b_dw given stats of h (b_dw cancels) -> bank BK
template<int BK>
__global__ void param_dw(const float* __restrict__ w, const float* __restrict__ g,
                         const float* __restrict__ be, float n, int C) {
  int c = threadIdx.x;
  if (c < C) {
    float mean = g_sum[c] / n;
    float var  = fmaxf(g_sqs[c] / n - mean * mean, 0.f);
    float r = rsqrtf(w[c]*w[c]*var + EPS);
    float a = w[c] * r * g[c];
    cfaP<BK>()[c] = a;
    cfbP<BK>()[c] = be[c] - a * mean;
  }
  __syncthreads();
  g_sum[c] = 0.f; g_sqs[c] = 0.f;
}

// Fold bank-1 cf into a [N][K] bf16 weight (in place) + bias
template<int SID>
__global__ void scale_fold(const float* __restrict__ bias_in, int N, int K) {
  u16* Wt = (SID == 0) ? g_w3t : g_projwt;
  float* badj = (SID == 0) ? g_b3adj : g_pbadj;
  int w = (blockIdx.x * blockDim.x + threadIdx.x) >> 6;
  int lane = threadIdx.x & 63;
  if (w >= N) return;
  float acc = 0.f;
  for (int k = lane; k < K; k += 64) {
    float wv = bf2f(Wt[(size_t)w*K + k]);
    acc = fmaf(g_cfb[k], wv, acc);
    Wt[(size_t)w*K + k] = f2bf(g_cfa[k] * wv);
  }
#pragma unroll
  for (int o = 32; o; o >>= 1) acc += __shfl_xor(acc, o, 64);
  if (lane == 0) badj[w] = bias_in[w] + acc;
}

// ---------------- K1: wave-autonomous gather + MLP1 + MLP2 ------------------
constexpr int K1_BLOCKS = 960;
__launch_bounds__(256)
__global__ void k1_edge(const int* __restrict__ esrc, const int* __restrict__ idx,
                        const float* __restrict__ b1v, const float* __restrict__ b2v) {
  __shared__ u16 sH[4][16][72];
  __shared__ float ssum[64], ssqs[64];
  const int tid = threadIdx.x;
  if (tid < 64) { ssum[tid] = 0.f; ssqs[tid] = 0.f; }
  __syncthreads();
  const int w = tid >> 6, lane = tid & 63, l15 = lane & 15, l4 = lane >> 4;
  u16 (*sh)[72] = sH[w];
  bf16x8 w1f[2][4], w2f[2][4];
#pragma unroll
  for (int ks = 0; ks < 2; ks++)
#pragma unroll
    for (int fc = 0; fc < 4; fc++) {
      w1f[ks][fc] = *reinterpret_cast<const bf16x8*>(g_w1t + (size_t)(fc*16+l15)*64 + ks*32 + l4*8);
      w2f[ks][fc] = *reinterpret_cast<const bf16x8*>(g_w2t + (size_t)(fc*16+l15)*64 + ks*32 + l4*8);
    }
  float b1r[4], b2r[4];
#pragma unroll
  for (int fc = 0; fc < 4; fc++) { b1r[fc] = b1v[fc*16+l15]; b2r[fc] = b2v[fc*16+l15]; }
  float s8[4] = {}, q8[4] = {};
  const int t0 = blockIdx.x * 4 + w;
  const int TSTRIDE = K1_BLOCKS * 4;
  int   s_cur = esrc[t0*16 + l15];
  uint4 x_cur = *reinterpret_cast<const uint4*>(g_xbf + (size_t)s_cur*32 + l4*8);
  float4 ps_cur = make_float4(0.f,0.f,0.f,0.f);
  if (l4 == 0) ps_cur = *reinterpret_cast<const float4*>(g_pos_s + (size_t)s_cur*4);
  float4 pc_cur = *reinterpret_cast<const float4*>(g_pos_s + (size_t)idx[t0]*4);
  int s_n1 = 0;
  if (t0 + TSTRIDE < NM) s_n1 = esrc[(t0 + TSTRIDE)*16 + l15];

  for (int t = t0; t < NM; t += TSTRIDE) {
    const int tn = t + TSTRIDE, tn2 = t + 2*TSTRIDE;
    int s_n2 = 0;
    if (tn2 < NM) s_n2 = esrc[tn2*16 + l15];
    uint4 x_nx = make_uint4(0,0,0,0);
    float4 ps_nx = ps_cur, pc_nx = pc_cur;
    if (tn < NM) {
      x_nx = *reinterpret_cast<const uint4*>(g_xbf + (size_t)s_n1*32 + l4*8);
      if (l4 == 0) ps_nx = *reinterpret_cast<const float4*>(g_pos_s + (size_t)s_n1*4);
      pc_nx = *reinterpret_cast<const float4*>(g_pos_s + (size_t)idx[tn]*4);
    }
    bf16x8 a0 = __builtin_bit_cast(bf16x8, x_cur);
    uint4 r4 = make_uint4(0,0,0,0);
    if (l4 == 0) {
      r4.x = pack2(ps_cur.x - pc_cur.x, ps_cur.y - pc_cur.y);
      r4.y = pack2(ps_cur.z - pc_cur.z, ps_cur.w - pc_cur.w);
    }
    bf16x8 a1 = __builtin_bit_cast(bf16x8, r4);
    f32x4 acc1[4] = {};
#pragma unroll
    for (int fc = 0; fc < 4; fc++) {
      acc1[fc] = __builtin_amdgcn_mfma_f32_16x16x32_bf16(a0, w1f[0][fc], acc1[fc], 0, 0, 0);
      acc1[fc] = __builtin_amdgcn_mfma_f32_16x16x32_bf16(a1, w1f[1][fc], acc1[fc], 0, 0, 0);
    }
#pragma unroll
    for (int fc = 0; fc < 4; fc++)
#pragma unroll
      for (int r = 0; r < 4; r++)
        sh[l4*4 + r][fc*16 + l15] = f2bf(fmaxf(acc1[fc][r] + b1r[fc], 0.f));
    bf16x8 h0  = *reinterpret_cast<const bf16x8*>(&sh[l15][l4*8]);
    bf16x8 h1v = *reinterpret_cast<const bf16x8*>(&sh[l15][32 + l4*8]);
    f32x4 acc2[4] = {};
#pragma unroll
    for (int fc = 0; fc < 4; fc++) {
      acc2[fc] = __builtin_amdgcn_mfma_f32_16x16x32_bf16(h0,  w2f[0][fc], acc2[fc], 0, 0, 0);
      acc2[fc] = __builtin_amdgcn_mfma_f32_16x16x32_bf16(h1v, w2f[1][fc], acc2[fc], 0, 0, 0);
    }
#pragma unroll
    for (int fc = 0; fc < 4; fc++)
#pragma unroll
      for (int r = 0; r < 4; r++) {
        float v = fmaxf(acc2[fc][r] + b2r[fc], 0.f);
        s8[fc] += v; q8[fc] += v*v;
        sh[l4*4 + r][fc*16 + l15] = f2bf(v);
      }
    uint4 p0 = *reinterpret_cast<const uint4*>(&sh[l15][l4*8]);
    uint4 p1 = *reinterpret_cast<const uint4*>(&sh[l15][32 + l4*8]);
    *reinterpret_cast<uint4*>(g_pre2 + (size_t)t*1024 + lane*8)       = p0;
    *reinterpret_cast<uint4*>(g_pre2 + (size_t)t*1024 + 512 + lane*8) = p1;
    s_cur = s_n1; x_cur = x_nx; ps_cur = ps_nx; pc_cur = pc_nx; s_n1 = s_n2;
  }
#pragma unroll
  for (int fc = 0; fc < 4; fc++) {
    float sv = s8[fc], qv = q8[fc];
    sv += __shfl_xor(sv, 16, 64); sv += __shfl_xor(sv, 32, 64);
    qv += __shfl_xor(qv, 16, 64); qv += __shfl_xor(qv, 32, 64);
    if (l4 == 0) { atomicAdd(&ssum[fc*16 + l15], sv); atomicAdd(&ssqs[fc*16 + l15], qv); }
  }
  __syncthreads();
  if (tid < 64) { atomicAdd(&g_sum[tid], ssum[tid]); atomicAdd(&g_sqs[tid], ssqs[tid]); }
}

// ---------------- K2: LDS-free MLP3 + stats + per-center max/min ------------
constexpr int K2_BLOCKS = 960;
__launch_bounds__(256)
__global__ void k2_edge() {
  __shared__ float ssum[128], ssqs[128];
  const int tid = threadIdx.x;
  if (tid < 128) { ssum[tid] = 0.f; ssqs[tid] = 0.f; }
  __syncthreads();
  const int lane = tid & 63, l15 = lane & 15, l4 = lane >> 4;
  const int wglobal = blockIdx.x * 4 + (tid >> 6);
  const int WSTRIDE = K2_BLOCKS * 4;
  bf16x8 w3f[2][8];
#pragma unroll
  for (int ks = 0; ks < 2; ks++)
#pragma unroll
    for (int fc = 0; fc < 8; fc++)
      w3f[ks][fc] = *reinterpret_cast<const bf16x8*>(g_w3t + (size_t)(fc*16 + l15)*64 + ks*32 + l4*8);
  float bv[8];
#pragma unroll
  for (int fc = 0; fc < 8; fc++) bv[fc] = g_b3adj[fc*16 + l15];
  float s[8] = {}, q[8] = {};
  int t = wglobal;
  uint4 an0 = make_uint4(0,0,0,0), an1 = an0;
  if (t < NM) {
    const uint4* p = reinterpret_cast<const uint4*>(g_pre2 + (size_t)t*1024 + lane*8);
    an0 = p[0]; an1 = p[64];
  }
  for (; t < NM; t += WSTRIDE) {
    uint4 a0 = an0, a1 = an1;
    int tn = t + WSTRIDE;
    if (tn < NM) {
      const uint4* p = reinterpret_cast<const uint4*>(g_pre2 + (size_t)tn*1024 + lane*8);
      an0 = p[0]; an1 = p[64];
    }
    bf16x8 af0 = __builtin_bit_cast(bf16x8, a0);
    bf16x8 af1 = __builtin_bit_cast(bf16x8, a1);
    f32x4 acc[8] = {};
#pragma unroll
    for (int fc = 0; fc < 8; fc++) {
      acc[fc] = __builtin_amdgcn_mfma_f32_16x16x32_bf16(af0, w3f[0][fc], acc[fc], 0, 0, 0);
      acc[fc] = __builtin_amdgcn_mfma_f32_16x16x32_bf16(af1, w3f[1][fc], acc[fc], 0, 0, 0);
    }
    u32 rbase = (u32)t * 128u;
#pragma unroll
    for (int fc = 0; fc < 8; fc++) {
      float v0 = fmaxf(acc[fc][0] + bv[fc], 0.f);
      float v1 = fmaxf(acc[fc][1] + bv[fc], 0.f);
      float v2 = fmaxf(acc[fc][2] + bv[fc], 0.f);
      float v3 = fmaxf(acc[fc][3] + bv[fc], 0.f);
      s[fc] += (v0 + v1) + (v2 + v3);
      q[fc] += (v0*v0 + v1*v1) + (v2*v2 + v3*v3);
      float mx = fmaxf(fmaxf(v0, v1), fmaxf(v2, v3));
      float mn = fminf(fminf(v0, v1), fminf(v2, v3));
      mx = fmaxf(mx, __shfl_xor(mx, 16, 64)); mx = fmaxf(mx, __shfl_xor(mx, 32, 64));
      mn = fminf(mn, __shfl_xor(mn, 16, 64)); mn = fminf(mn, __shfl_xor(mn, 32, 64));
      if (l4 == (fc & 3))
        g_mm[rbase + fc*16 + l15] = (u32)f2bf(mx) | ((u32)f2bf(mn) << 16);
    }
  }
#pragma unroll
  for (int fc = 0; fc < 8; fc++) {
    float sv = s[fc], qv = q[fc];
    sv += __shfl_xor(sv, 16, 64); sv += __shfl_xor(sv, 32, 64);
    qv += __shfl_xor(qv, 16, 64); qv += __shfl_xor(qv, 32, 64);
    if (l4 == 0) { atomicAdd(&ssum[fc*16 + l15], sv); atomicAdd(&ssqs[fc*16 + l15], qv); }
  }
  __syncthreads();
  if (tid < 128) { atomicAdd(&g_sum[tid], ssum[tid]); atomicAdd(&g_sqs[tid], ssqs[tid]); }
}

// K3: agg = bn3-affine of packed max/min (sign-select); write f32 residual + bf16
__global__ void k3_agg() {
  int i4 = (blockIdx.x * 256 + threadIdx.x) * 4;
  if (i4 >= NM * 128) return;
  int c = i4 & 127;
  uint4 mm = *reinterpret_cast<const uint4*>(g_mm + i4);
  float4 a = *reinterpret_cast<const float4*>(g_cfa + c);
  float4 b = *reinterpret_cast<const float4*>(g_cfb + c);
  u32 u[4] = {mm.x, mm.y, mm.z, mm.w};
  float av[4] = {a.x, a.y, a.z, a.w};
  float bb[4] = {b.x, b.y, b.z, b.w};
  float4 r;
  float* rr = &r.x;
#pragma unroll
  for (int j = 0; j < 4; j++) {
    float mx = bf2f((u16)(u[j] & 0xFFFFu));
    float mn = bf2f((u16)(u[j] >> 16));
    rr[j] = av[j] > 0.f ? fmaf(av[j], mx, bb[j]) : fmaf(av[j], mn, bb[j]);
  }
  *reinterpret_cast<float4*>(g_agg + i4) = r;
  uint2 pk; pk.x = pack2(r.x, r.y); pk.y = pack2(r.z, r.w);
  *reinterpret_cast<uint2*>(g_aggbf + i4) = pk;
}

// ---------------- MFMA GEMM (R17 + bijective XCD-chunked block swizzle) ------
// T1: consecutive bids (the 4 N-panels sharing an A-panel) -> same XCD L2.
template<int AID, int WID, int OID, int NPAN, bool OUT_BF16, bool BIAS_DEV>
__launch_bounds__(256, 4)
__global__ void gemm_mfma(const float* __restrict__ bias, int Mrows, int Kdim) {
  const int Ncols = NPAN * 128;
  const u16* __restrict__ A  = ubufsel<AID>();
  const u16* __restrict__ Bt = wsel<WID>();
  __shared__ u16 sLDS[16384];          // 32KB: A bufs [0..8191], B bufs [8192..]
  __shared__ float ssum[128], ssqs[128];
  u16* sA = sLDS;
  u16* sB = sLDS + 8192;
  const int tid = threadIdx.x;
  // bijective chunked XCD swizzle (m204): xcd = orig%8 gets a contiguous run
  const int nwg = gridDim.x;
  const int orig = blockIdx.x;
  const int qc = nwg >> 3, xr = nwg & 7;
  const int xcd = orig & 7, ii = orig >> 3;
  const int bid = (xcd < xr ? xcd * (qc + 1) : xr * (qc + 1) + (xcd - xr) * qc) + ii;
  const int m0 = (bid / NPAN) * 128, n0 = (bid % NPAN) * 128;
  if (tid < 128) { ssum[tid] = 0.f; ssqs[tid] = 0.f; }
  const int wave = tid >> 6, lane = tid & 63, l15 = lane & 15, l4 = lane >> 4;
  const int wr = wave >> 1, wc = wave & 1;
  const int ckk = (lane & 3) * 8;      // linear per-lane K offset (proven)
  f32x4 acc[4][4] = {};
  const int nt = Kdim >> 5;

  auto STAGE = [&](int buf, int t) {
    const int k0 = t * 32;
#pragma unroll
    for (int i = 0; i < 2; i++) {
      const int c = wave * 2 + i;
      int ar = m0 + c * 16 + (lane >> 2);
      if (ar >= Mrows) ar = Mrows - 1;               // clamp; results unused
      const int br = n0 + c * 16 + (lane >> 2);
      __builtin_amdgcn_global_load_lds(AS_GLOBAL(A  + (size_t)ar * Kdim + k0 + ckk),
                                       AS_LDS(sA + buf*4096 + c*512), 16, 0, 0);
      __builtin_amdgcn_global_load_lds(AS_GLOBAL(Bt + (size_t)br * Kdim + k0 + ckk),
                                       AS_LDS(sB + buf*4096 + c*512), 16, 0, 0);
    }
  };

  STAGE(0, 0);
  __syncthreads();                 // drains vmcnt -> buf0 ready
  int cur = 0;
  for (int t = 0; t < nt; ++t) {
    if (t + 1 < nt) STAGE(cur ^ 1, t + 1);   // issue next tile; hides under MFMA
    bf16x8 af[4], bf4[4];
#pragma unroll
    for (int fr = 0; fr < 4; fr++) {
      int r = wr*64 + fr*16 + l15;
      af[fr] = *reinterpret_cast<const bf16x8*>(sA + cur*4096 + r*32 + l4*8);
    }
#pragma unroll
    for (int fc = 0; fc < 4; fc++) {
      int r = wc*64 + fc*16 + l15;
      bf4[fc] = *reinterpret_cast<const bf16x8*>(sB + cur*4096 + r*32 + l4*8);
    }
#pragma unroll
    for (int fr = 0; fr < 4; fr++)
#pragma unroll
      for (int fc = 0; fc < 4; fc++)
        acc[fr][fc] = __builtin_amdgcn_mfma_f32_16x16x32_bf16(af[fr], bf4[fc], acc[fr][fc], 0, 0, 0);
    if (t + 1 < nt) { __syncthreads(); cur ^= 1; }
  }

  __syncthreads();   // all LDS reads done -> safe to reuse sLDS for C-bounce
  const int orow = m0 + wr*64 + l4*4;
#pragma unroll
  for (int fc = 0; fc < 4; fc++) {
    int col = n0 + wc*64 + fc*16 + l15;
    float bvv = BIAS_DEV ? g_pbadj[col] : bias[col];
    float s = 0.f, q = 0.f;
#pragma unroll
    for (int fr = 0; fr < 4; fr++)
#pragma unroll
      for (int r = 0; r < 4; r++) {
        int row = orow + fr*16 + r;
        if (row < Mrows) {
          float v = acc[fr][fc][r] + bvv;
          s += v; q += v*v;
          if (OUT_BF16) sLDS[(size_t)(wr*64 + fr*16 + l4*4 + r)*128 + wc*64 + fc*16 + l15] = f2bf(v);
          else          g_obuf[(size_t)row*Ncols + col] = v;
        }
      }
    atomicAdd(&ssum[wc*64 + fc*16 + l15], s);
    atomicAdd(&ssqs[wc*64 + fc*16 + l15], q);
  }
  __syncthreads();
  if (OUT_BF16) {
    // coalesced copy-out: thread -> 64 u16 (half a row, 128B) = 8 x uint4
    const int r2 = tid >> 1, hh = tid & 1;
    if (m0 + r2 < Mrows) {
      const uint4* src = reinterpret_cast<const uint4*>(sLDS + r2*128 + hh*64);
      uint4* dst = reinterpret_cast<uint4*>(obufsel<OID>() + (size_t)(m0 + r2)*Ncols + n0 + hh*64);
#pragma unroll
      for (int j = 0; j < 8; j++) dst[j] = src[j];
    }
  }
  if (tid < 128) { atomicAdd(&g_sum[n0 + tid], ssum[tid]); atomicAdd(&g_sqs[n0 + tid], ssqs[tid]); }
}

// ---------------- EW chain: y = chain of relu(a_i*x+b_i), banks 1..NCH ------
template<int INID, int OUTID, int NCH, bool WRITE, bool STATS>
__launch_bounds__(256)
__global__ void ew_chain(int rows) {
  const u16* __restrict__ X = ubufsel<INID>();
  u16* __restrict__ Y = obufsel<OUTID>();
  __shared__ float ssum[512], ssqs[512];
  const int tid = threadIdx.x;
  if (STATS) {
    ssum[tid] = 0.f; ssum[tid+256] = 0.f; ssqs[tid] = 0.f; ssqs[tid+256] = 0.f;
    __syncthreads();
  }
  const int c0 = (tid & 63) * 8;
  const int rl = tid >> 6;
  float a1[8], b1[8], a2[8], b2[8], a3[8], b3[8];
#pragma unroll
  for (int j = 0; j < 8; j++) {
    a1[j] = g_cfa[c0+j]; b1[j] = g_cfb[c0+j];
    if constexpr (NCH >= 2) { a2[j] = g_cfa2[c0+j]; b2[j] = g_cfb2[c0+j]; }
    if constexpr (NCH >= 3) { a3[j] = g_cfa3[c0+j]; b3[j] = g_cfb3[c0+j]; }
  }
  float s[8] = {}, q[8] = {};
  for (int r = blockIdx.x*4 + rl; r < rows; r += gridDim.x*4) {
    uint4 v = *reinterpret_cast<const uint4*>(X + (size_t)r*512 + c0);
    u32 u[4] = {v.x, v.y, v.z, v.w}, o[4];
#pragma unroll
    for (int t = 0; t < 4; t++) {
      float lo = bf2f((u16)(u[t] & 0xFFFFu));
      float hi = bf2f((u16)(u[t] >> 16));
      lo = fmaxf(fmaf(a1[2*t],   lo, b1[2*t]),   0.f);
      hi = fmaxf(fmaf(a1[2*t+1], hi, b1[2*t+1]), 0.f);
      if constexpr (NCH >= 2) {
        lo = fmaxf(fmaf(a2[2*t],   lo, b2[2*t]),   0.f);
        hi = fmaxf(fmaf(a2[2*t+1], hi, b2[2*t+1]), 0.f);
      }
      if constexpr (NCH >= 3) {
        lo = fmaxf(fmaf(a3[2*t],   lo, b3[2*t]),   0.f);
        hi = fmaxf(fmaf(a3[2*t+1], hi, b3[2*t+1]), 0.f);
      }
      if (STATS) { s[2*t] += lo; q[2*t] += lo*lo; s[2*t+1] += hi; q[2*t+1] += hi*hi; }
      if (WRITE) o[t] = (u32)f2bf(lo) | ((u32)f2bf(hi) << 16);
    }
    if (WRITE) *reinterpret_cast<uint4*>(Y + (size_t)r*512 + c0) = make_uint4(o[0], o[1], o[2], o[3]);
  }
  if (STATS) {
#pragma unroll
    for (int j = 0; j < 8; j++) { atomicAdd(&ssum[c0+j], s[j]); atomicAdd(&ssqs[c0+j], q[j]); }
    __syncthreads();
    atomicAdd(&g_sum[tid],     ssum[tid]);     atomicAdd(&g_sqs[tid],     ssqs[tid]);
    atomicAdd(&g_sum[tid+256], ssum[tid+256]); atomicAdd(&g_sqs[tid+256], ssqs[tid+256]);
  }
}

__global__ void final_out(float* __restrict__ out) {
  int i4 = (blockIdx.x * 256 + threadIdx.x) * 4;
  if (i4 >= NM * 128) return;
  int c = i4 & 127;
  float4 o  = *reinterpret_cast<const float4*>(g_obuf + i4);
  float4 ag = *reinterpret_cast<const float4*>(g_agg + i4);
  float4 a  = *reinterpret_cast<const float4*>(g_cfa + c);
  float4 b  = *reinterpret_cast<const float4*>(g_cfb + c);
  float4 r;
  r.x = fmaxf(fmaf(a.x, o.x, b.x) + ag.x, 0.f);
  r.y = fmaxf(fmaf(a.y, o.y, b.y) + ag.y, 0.f);
  r.z = fmaxf(fmaf(a.z, o.z, b.z) + ag.z, 0.f);
  r.w = fmaxf(fmaf(a.w, o.w, b.w) + ag.w, 0.f);
  *reinterpret_cast<float4*>(out + i4) = r;
}

// ---------------- host launch ------------------------------------------------
extern "C" void kernel_launch(void* const* d_in, const int* in_sizes, int n_in,
                              void* d_out, int out_size, void* d_ws, size_t ws_size,
                              hipStream_t stream) {
  const float* x     = (const float*)d_in[0];
  const float* pos   = (const float*)d_in[1];
  const int*   batch = (const int*)  d_in[2];
  const float* refl  = (const float*)d_in[3];
  const float* sf    = (const float*)d_in[4];
  const int*   idx   = (const int*)  d_in[5];
  const int*   esrc  = (const int*)  d_in[6];
  const float* W1  = (const float*)d_in[8];
  const float* b1  = (const float*)d_in[9];
  const float* W2  = (const float*)d_in[10];
  const float* b2  = (const float*)d_in[11];
  const float* g2  = (const float*)d_in[12];
  const float* be2 = (const float*)d_in[13];
  const float* W3  = (const float*)d_in[14];
  const float* b3  = (const float*)d_in[15];
  const float* g3  = (const float*)d_in[16];
  const float* be3 = (const float*)d_in[17];
  const float* expW  = (const float*)d_in[24];
  const float* expb  = (const float*)d_in[25];
  const float* expg  = (const float*)d_in[26];
  const float* expbe = (const float*)d_in[27];
  const float* dww  = (const float*)d_in[28];
  const float* dwg  = (const float*)d_in[30];
  const float* dwbe = (const float*)d_in[31];
  const float* pwW  = (const float*)d_in[32];
  const float* pwb  = (const float*)d_in[33];
  const float* pwg  = (const float*)d_in[34];
  const float* pwbe = (const float*)d_in[35];
  const float* cg   = (const float*)d_in[36];
  const float* cbe  = (const float*)d_in[37];
  const float* projW  = (const float*)d_in[38];
  const float* projb  = (const float*)d_in[39];
  const float* projg  = (const float*)d_in[40];
  const float* projbe = (const float*)d_in[41];
  float* out = (float*)d_out;

  const float fNE = (float)NE, fNM = (float)NM;

  prep_weights<<<2624, 256, 0, stream>>>(W1, W2, W3, expW, pwW, projW);
  prep_pos_x<<<(NP + 255)/256, 256, 0, stream>>>(pos, batch, refl, sf, x);
  tail_out<<<(NM + 255)/256, 256, 0, stream>>>(pos, batch, refl, sf, idx, out);
  zero_stats<<<1, 512, 0, stream>>>();

  k1_edge<<<K1_BLOCKS, 256, 0, stream>>>(esrc, idx, b1, b2);          // stats(pre2)
  param_bn<1><<<1, 512, 0, stream>>>(g2, be2, fNE, 64);
  scale_fold<0><<<32, 256, 0, stream>>>(b3, 128, 64);                 // fold bn2 into W3/b3
  k2_edge<<<K2_BLOCKS, 256, 0, stream>>>();                           // stats(pre3) + max/min
  param_bn<1><<<1, 512, 0, stream>>>(g3, be3, fNE, 128);
  k3_agg<<<NM*128/1024, 256, 0, stream>>>();

  // t1 = agg @ expW + expb   (stats(t1))
  gemm_mfma<1, 3, 2, 4, true, false><<<469*4, 256, 0, stream>>>(expb, NM, 128);
  param_bn<1><<<1, 512, 0, stream>>>(expg, expbe, fNM, 512);          // bn_exp -> bank1
  ew_chain<2, 3, 1, false, true><<<1024, 256, 0, stream>>>(NM);       // stats(e), no write
  param_dw<2><<<1, 512, 0, stream>>>(dww, dwg, dwbe, fNM, 512);       // dw0 -> bank2
  ew_chain<2, 3, 2, true, false><<<1024, 256, 0, stream>>>(NM);       // z0 -> bufB
  // p0 = z0 @ pw0 + pwb0   (stats(p0))
  gemm_mfma<3, 4, 2, 4, true, false><<<469*4, 256, 0, stream>>>(pwb, NM, 512);
  param_bn<1><<<1, 512, 0, stream>>>(pwg, pwbe, fNM, 512);            // bn_pw0 -> bank1
  ew_chain<2, 3, 1, false, true><<<1024, 256, 0, stream>>>(NM);       // stats(v0)
  param_bn<2><<<1, 512, 0, stream>>>(cg, cbe, fNM, 512);              // bn_c0 -> bank2
  ew_chain<2, 3, 2, false, true><<<1024, 256, 0, stream>>>(NM);       // stats(cmid)
  param_dw<3><<<1, 512, 0, stream>>>(dww + 512, dwg + 512, dwbe + 512, fNM, 512); // dw1 -> bank3
  ew_chain<2, 3, 3, true, false><<<1024, 256, 0, stream>>>(NM);       // z1 -> bufB
  // p1 = z1 @ pw1 + pwb1   (stats(p1))
  gemm_mfma<3, 5, 2, 4, true, false><<<469*4, 256, 0, stream>>>(pwb + 512, NM, 512);
  param_bn<1><<<1, 512, 0, stream>>>(pwg + 512, pwbe + 512, fNM, 512);// bn_pw1 -> bank1
  ew_chain<2, 2, 1, true, true><<<1024, 256, 0, stream>>>(NM);        // v1 -> bufA (in place), stats(v1)
  param_bn<1><<<1, 512, 0, stream>>>(cg + 512, cbe + 512, fNM, 512);  // bn_c1 -> bank1
  scale_fold<1><<<32, 256, 0, stream>>>(projb, 128, 512);             // fold c1-bn into projW/projb
  // o = v1 @ projW' + pbadj  (f32 out, N=128)
  gemm_mfma<2, 6, 0, 1, false, true><<<469, 256, 0, stream>>>(projb, NM, 512);
  param_bn<1><<<1, 512, 0, stream>>>(projg, projbe, fNM, 128);
  final_out<<<NM*128/1024, 256, 0, stream>>>(out);
}

// Round 19
// 686.872 us; speedup vs baseline: 1.1153x; 1.1153x over previous
//
#include <hip/hip_runtime.h>
#include <hip/hip_bf16.h>
#include <cstdint>

#define DEV_INLINE __device__ __forceinline__

typedef unsigned short u16;
typedef unsigned int   u32;
typedef short bf16x8 __attribute__((ext_vector_type(8)));
typedef float f32x4  __attribute__((ext_vector_type(4)));

#define AS_GLOBAL(p) ((const __attribute__((address_space(1))) void*)(p))
#define AS_LDS(p)    ((__attribute__((address_space(3))) void*)(p))

constexpr int NP = 120000, NB = 8, NM = 60000, KNN = 16;
constexpr int NE = NM * KNN;          // 960000
constexpr float EPS = 1e-5f;

constexpr size_t O_POS   = (size_t)NM * 128;
constexpr size_t O_BATCH = O_POS + (size_t)NM * 3;
constexpr size_t O_REFL  = O_BATCH + NM;
constexpr size_t O_SF    = O_REFL + NM;

// ---------------- device-global buffers -------------------------------------
__device__ float  g_pos_s[(size_t)NP * 4];
__device__ u16    g_xbf[(size_t)NP * 32];         // x in bf16
__device__ u16    g_pre2[(size_t)NE * 64];        // fragment-tile layout
__device__ u32    g_mm[(size_t)NM * 128];         // packed bf16 {lo=max, hi=min}
__device__ float  g_agg[(size_t)NM * 128];        // f32 residual
__device__ u16    g_aggbf[(size_t)NM * 128];      // bf16 GEMM input
__device__ u16    g_bufA[(size_t)NM * 512];
__device__ u16    g_bufB[(size_t)NM * 512];
__device__ float  g_obuf[(size_t)NM * 128];
__device__ float  g_sum[512], g_sqs[512];
__device__ float  g_cfa[512],  g_cfb[512];    // bank 1
__device__ float  g_cfa2[512], g_cfb2[512];   // bank 2
__device__ float  g_cfa3[512], g_cfb3[512];   // bank 3
__device__ float  g_b3adj[128], g_pbadj[128];
// transposed bf16 weights [N][K]
__device__ u16 g_w1t[64 * 64];      // K padded 36->64 (zeros)
__device__ u16 g_w2t[64 * 64];
__device__ u16 g_w3t[128 * 64];     // bn2-folded in place per launch
__device__ u16 g_expwt[512 * 128];
__device__ u16 g_pw0t[512 * 512];
__device__ u16 g_pw1t[512 * 512];
__device__ u16 g_projwt[128 * 512]; // c1-bn-folded in place per launch

template<int ID> DEV_INLINE const u16* ubufsel() {
  if constexpr (ID == 1) return g_aggbf;
  else if constexpr (ID == 2) return g_bufA;
  else return g_bufB;
}
template<int ID> DEV_INLINE u16* obufsel() {
  if constexpr (ID == 2) return g_bufA;
  else return g_bufB;
}
template<int ID> DEV_INLINE const u16* wsel() {
  if constexpr (ID == 3) return g_expwt;
  else if constexpr (ID == 4) return g_pw0t;
  else if constexpr (ID == 5) return g_pw1t;
  else return g_projwt;
}
template<int BK> DEV_INLINE float* cfaP() {
  if constexpr (BK == 1) return g_cfa; else if constexpr (BK == 2) return g_cfa2; else return g_cfa3;
}
template<int BK> DEV_INLINE float* cfbP() {
  if constexpr (BK == 1) return g_cfb; else if constexpr (BK == 2) return g_cfb2; else return g_cfb3;
}

// ---------------- helpers ----------------------------------------------------
DEV_INLINE float bf2f(u16 u) { u32 x = (u32)u << 16; float f; __builtin_memcpy(&f, &x, 4); return f; }
DEV_INLINE u16 f2bf(float f) {
  u32 x; __builtin_memcpy(&x, &f, 4);
  return (u16)((x + 0x7FFFu + ((x >> 16) & 1u)) >> 16);
}
DEV_INLINE u32 pack2(float a, float b) { return (u32)f2bf(a) | ((u32)f2bf(b) << 16); }

// ---------------- tiny kernels ----------------------------------------------
__global__ void prep_pos_x(const float* __restrict__ pos, const int* __restrict__ batch,
                           const float* __restrict__ refl, const float* __restrict__ sf,
                           const float* __restrict__ x) {
  int i = blockIdx.x * blockDim.x + threadIdx.x;
  if (i >= NP) return;
  float s = sf[batch[i]];
  float4 v;
  v.x = pos[(size_t)i*3+0] / s;
  v.y = pos[(size_t)i*3+1] / s;
  v.z = pos[(size_t)i*3+2] / s;
  v.w = refl[i];   // gate == 1 exactly
  *reinterpret_cast<float4*>(g_pos_s + (size_t)i*4) = v;
  const float4* xr = reinterpret_cast<const float4*>(x + (size_t)i*32);
#pragma unroll
  for (int q = 0; q < 4; q++) {
    float4 a = xr[q*2], b = xr[q*2+1];
    uint4 u = make_uint4(pack2(a.x,a.y), pack2(a.z,a.w), pack2(b.x,b.y), pack2(b.z,b.w));
    *reinterpret_cast<uint4*>(g_xbf + (size_t)i*32 + q*8) = u;
  }
}

__global__ void tail_out(const float* __restrict__ pos, const int* __restrict__ batch,
                         const float* __restrict__ refl, const float* __restrict__ sf,
                         const int* __restrict__ idx, float* __restrict__ out) {
  int i = blockIdx.x * blockDim.x + threadIdx.x;
  if (i < NM) {
    int p = idx[i];
    out[O_POS + (size_t)i*3+0] = pos[(size_t)p*3+0];
    out[O_POS + (size_t)i*3+1] = pos[(size_t)p*3+1];
    out[O_POS + (size_t)i*3+2] = pos[(size_t)p*3+2];
    out[O_BATCH + i] = (float)batch[p];
    out[O_REFL  + i] = refl[p];
  }
  if (i < NB) out[O_SF + i] = sf[i];
}

__global__ void zero_stats() {
  int t = threadIdx.x;
  g_sum[t] = 0.f; g_sqs[t] = 0.f;
}

// transpose + bf16-convert all weights (one kernel)
__global__ void prep_weights(const float* __restrict__ W1, const float* __restrict__ W2,
                             const float* __restrict__ W3, const float* __restrict__ expW,
                             const float* __restrict__ pwW, const float* __restrict__ projW) {
  int i = blockIdx.x * 256 + threadIdx.x;
  const int s0 = 4096, s1 = 4096, s2 = 8192, s3 = 65536, s4 = 262144, s5 = 262144, s6 = 65536;
  if (i < s0) { int n = i >> 6, k = i & 63; g_w1t[i] = (k < 36) ? f2bf(W1[k*64 + n]) : (u16)0; return; }
  i -= s0;
  if (i < s1) { int n = i >> 6, k = i & 63; g_w2t[i] = f2bf(W2[k*64 + n]); return; }
  i -= s1;
  if (i < s2) { int n = i >> 6, k = i & 63; g_w3t[i] = f2bf(W3[k*128 + n]); return; }
  i -= s2;
  if (i < s3) { int n = i >> 7, k = i & 127; g_expwt[i] = f2bf(expW[k*512 + n]); return; }
  i -= s3;
  if (i < s4) { int n = i >> 9, k = i & 511; g_pw0t[i] = f2bf(pwW[k*512 + n]); return; }
  i -= s4;
  if (i < s5) { int n = i >> 9, k = i & 511; g_pw1t[i] = f2bf(pwW[262144 + k*512 + n]); return; }
  i -= s5;
  if (i < s6) { int n = i >> 9, k = i & 511; g_projwt[i] = f2bf(projW[k*128 + n]); return; }
}

// param: BN params -> bank BK from stats in g_sum/g_sqs; then zero stats
template<int BK>
__global__ void param_bn(const float* __restrict__ g, const float* __restrict__ be,
                         float n, int C) {
  int c = threadIdx.x;
  if (c < C) {
    float mean = g_sum[c] / n;
    float var  = fmaxf(g_sqs[c] / n - mean * mean, 0.f);
    float a = g[c] * rsqrtf(var + EPS);
    cfaP<BK>()[c] = a;
    cfbP<BK>()[c] = be[c] - a * mean;
  }
  __syncthreads();
  g_sum[c] = 0.f; g_sqs[c] = 0.f;
}

// BN of u = w*h + b_dw given stats of h (b_dw cancels) -> bank BK
template<int BK>
__global__ void param_dw(const float* __restrict__ w, const float* __restrict__ g,
                         const float* __restrict__ be, float n, int C) {
  int c = threadIdx.x;
  if (c < C) {
    float mean = g_sum[c] / n;
    float var  = fmaxf(g_sqs[c] / n - mean * mean, 0.f);
    float r = rsqrtf(w[c]*w[c]*var + EPS);
    float a = w[c] * r * g[c];
    cfaP<BK>()[c] = a;
    cfbP<BK>()[c] = be[c] - a * mean;
  }
  __syncthreads();
  g_sum[c] = 0.f; g_sqs[c] = 0.f;
}

// Fold bank-1 cf into a [N][K] bf16 weight (in place) + bias
template<int SID>
__global__ void scale_fold(const float* __restrict__ bias_in, int N, int K) {
  u16* Wt = (SID == 0) ? g_w3t : g_projwt;
  float* badj = (SID == 0) ? g_b3adj : g_pbadj;
  int w = (blockIdx.x * blockDim.x + threadIdx.x) >> 6;
  int lane = threadIdx.x & 63;
  if (w >= N) return;
  float acc = 0.f;
  for (int k = lane; k < K; k += 64) {
    float wv = bf2f(Wt[(size_t)w*K + k]);
    acc = fmaf(g_cfb[k], wv, acc);
    Wt[(size_t)w*K + k] = f2bf(g_cfa[k] * wv);
  }
#pragma unroll
  for (int o = 32; o; o >>= 1) acc += __shfl_xor(acc, o, 64);
  if (lane == 0) badj[w] = bias_in[w] + acc;
}

// ---------------- K1: wave-autonomous gather + MLP1 + MLP2 ------------------
constexpr int K1_BLOCKS = 960;
__launch_bounds__(256)
__global__ void k1_edge(const int* __restrict__ esrc, const int* __restrict__ idx,
                        const float* __restrict__ b1v, const float* __restrict__ b2v) {
  __shared__ u16 sH[4][16][72];
  __shared__ float ssum[64], ssqs[64];
  const int tid = threadIdx.x;
  if (tid < 64) { ssum[tid] = 0.f; ssqs[tid] = 0.f; }
  __syncthreads();
  const int w = tid >> 6, lane = tid & 63, l15 = lane & 15, l4 = lane >> 4;
  u16 (*sh)[72] = sH[w];
  bf16x8 w1f[2][4], w2f[2][4];
#pragma unroll
  for (int ks = 0; ks < 2; ks++)
#pragma unroll
    for (int fc = 0; fc < 4; fc++) {
      w1f[ks][fc] = *reinterpret_cast<const bf16x8*>(g_w1t + (size_t)(fc*16+l15)*64 + ks*32 + l4*8);
      w2f[ks][fc] = *reinterpret_cast<const bf16x8*>(g_w2t + (size_t)(fc*16+l15)*64 + ks*32 + l4*8);
    }
  float b1r[4], b2r[4];
#pragma unroll
  for (int fc = 0; fc < 4; fc++) { b1r[fc] = b1v[fc*16+l15]; b2r[fc] = b2v[fc*16+l15]; }
  float s8[4] = {}, q8[4] = {};
  const int t0 = blockIdx.x * 4 + w;
  const int TSTRIDE = K1_BLOCKS * 4;
  int   s_cur = esrc[t0*16 + l15];
  uint4 x_cur = *reinterpret_cast<const uint4*>(g_xbf + (size_t)s_cur*32 + l4*8);
  float4 ps_cur = make_float4(0.f,0.f,0.f,0.f);
  if (l4 == 0) ps_cur = *reinterpret_cast<const float4*>(g_pos_s + (size_t)s_cur*4);
  float4 pc_cur = *reinterpret_cast<const float4*>(g_pos_s + (size_t)idx[t0]*4);
  int s_n1 = 0;
  if (t0 + TSTRIDE < NM) s_n1 = esrc[(t0 + TSTRIDE)*16 + l15];

  for (int t = t0; t < NM; t += TSTRIDE) {
    const int tn = t + TSTRIDE, tn2 = t + 2*TSTRIDE;
    int s_n2 = 0;
    if (tn2 < NM) s_n2 = esrc[tn2*16 + l15];
    uint4 x_nx = make_uint4(0,0,0,0);
    float4 ps_nx = ps_cur, pc_nx = pc_cur;
    if (tn < NM) {
      x_nx = *reinterpret_cast<const uint4*>(g_xbf + (size_t)s_n1*32 + l4*8);
      if (l4 == 0) ps_nx = *reinterpret_cast<const float4*>(g_pos_s + (size_t)s_n1*4);
      pc_nx = *reinterpret_cast<const float4*>(g_pos_s + (size_t)idx[tn]*4);
    }
    bf16x8 a0 = __builtin_bit_cast(bf16x8, x_cur);
    uint4 r4 = make_uint4(0,0,0,0);
    if (l4 == 0) {
      r4.x = pack2(ps_cur.x - pc_cur.x, ps_cur.y - pc_cur.y);
      r4.y = pack2(ps_cur.z - pc_cur.z, ps_cur.w - pc_cur.w);
    }
    bf16x8 a1 = __builtin_bit_cast(bf16x8, r4);
    f32x4 acc1[4] = {};
#pragma unroll
    for (int fc = 0; fc < 4; fc++) {
      acc1[fc] = __builtin_amdgcn_mfma_f32_16x16x32_bf16(a0, w1f[0][fc], acc1[fc], 0, 0, 0);
      acc1[fc] = __builtin_amdgcn_mfma_f32_16x16x32_bf16(a1, w1f[1][fc], acc1[fc], 0, 0, 0);
    }
#pragma unroll
    for (int fc = 0; fc < 4; fc++)
#pragma unroll
      for (int r = 0; r < 4; r++)
        sh[l4*4 + r][fc*16 + l15] = f2bf(fmaxf(acc1[fc][r] + b1r[fc], 0.f));
    bf16x8 h0  = *reinterpret_cast<const bf16x8*>(&sh[l15][l4*8]);
    bf16x8 h1v = *reinterpret_cast<const bf16x8*>(&sh[l15][32 + l4*8]);
    f32x4 acc2[4] = {};
#pragma unroll
    for (int fc = 0; fc < 4; fc++) {
      acc2[fc] = __builtin_amdgcn_mfma_f32_16x16x32_bf16(h0,  w2f[0][fc], acc2[fc], 0, 0, 0);
      acc2[fc] = __builtin_amdgcn_mfma_f32_16x16x32_bf16(h1v, w2f[1][fc], acc2[fc], 0, 0, 0);
    }
#pragma unroll
    for (int fc = 0; fc < 4; fc++)
#pragma unroll
      for (int r = 0; r < 4; r++) {
        float v = fmaxf(acc2[fc][r] + b2r[fc], 0.f);
        s8[fc] += v; q8[fc] += v*v;
        sh[l4*4 + r][fc*16 + l15] = f2bf(v);
      }
    uint4 p0 = *reinterpret_cast<const uint4*>(&sh[l15][l4*8]);
    uint4 p1 = *reinterpret_cast<const uint4*>(&sh[l15][32 + l4*8]);
    *reinterpret_cast<uint4*>(g_pre2 + (size_t)t*1024 + lane*8)       = p0;
    *reinterpret_cast<uint4*>(g_pre2 + (size_t)t*1024 + 512 + lane*8) = p1;
    s_cur = s_n1; x_cur = x_nx; ps_cur = ps_nx; pc_cur = pc_nx; s_n1 = s_n2;
  }
#pragma unroll
  for (int fc = 0; fc < 4; fc++) {
    float sv = s8[fc], qv = q8[fc];
    sv += __shfl_xor(sv, 16, 64); sv += __shfl_xor(sv, 32, 64);
    qv += __shfl_xor(qv, 16, 64); qv += __shfl_xor(qv, 32, 64);
    if (l4 == 0) { atomicAdd(&ssum[fc*16 + l15], sv); atomicAdd(&ssqs[fc*16 + l15], qv); }
  }
  __syncthreads();
  if (tid < 64) { atomicAdd(&g_sum[tid], ssum[tid]); atomicAdd(&g_sqs[tid], ssqs[tid]); }
}

// ---------------- K2: LDS-free MLP3 + stats + per-center max/min ------------
constexpr int K2_BLOCKS = 960;
__launch_bounds__(256)
__global__ void k2_edge() {
  __shared__ float ssum[128], ssqs[128];
  const int tid = threadIdx.x;
  if (tid < 128) { ssum[tid] = 0.f; ssqs[tid] = 0.f; }
  __syncthreads();
  const int lane = tid & 63, l15 = lane & 15, l4 = lane >> 4;
  const int wglobal = blockIdx.x * 4 + (tid >> 6);
  const int WSTRIDE = K2_BLOCKS * 4;
  bf16x8 w3f[2][8];
#pragma unroll
  for (int ks = 0; ks < 2; ks++)
#pragma unroll
    for (int fc = 0; fc < 8; fc++)
      w3f[ks][fc] = *reinterpret_cast<const bf16x8*>(g_w3t + (size_t)(fc*16 + l15)*64 + ks*32 + l4*8);
  float bv[8];
#pragma unroll
  for (int fc = 0; fc < 8; fc++) bv[fc] = g_b3adj[fc*16 + l15];
  float s[8] = {}, q[8] = {};
  int t = wglobal;
  uint4 an0 = make_uint4(0,0,0,0), an1 = an0;
  if (t < NM) {
    const uint4* p = reinterpret_cast<const uint4*>(g_pre2 + (size_t)t*1024 + lane*8);
    an0 = p[0]; an1 = p[64];
  }
  for (; t < NM; t += WSTRIDE) {
    uint4 a0 = an0, a1 = an1;
    int tn = t + WSTRIDE;
    if (tn < NM) {
      const uint4* p = reinterpret_cast<const uint4*>(g_pre2 + (size_t)tn*1024 + lane*8);
      an0 = p[0]; an1 = p[64];
    }
    bf16x8 af0 = __builtin_bit_cast(bf16x8, a0);
    bf16x8 af1 = __builtin_bit_cast(bf16x8, a1);
    f32x4 acc[8] = {};
#pragma unroll
    for (int fc = 0; fc < 8; fc++) {
      acc[fc] = __builtin_amdgcn_mfma_f32_16x16x32_bf16(af0, w3f[0][fc], acc[fc], 0, 0, 0);
      acc[fc] = __builtin_amdgcn_mfma_f32_16x16x32_bf16(af1, w3f[1][fc], acc[fc], 0, 0, 0);
    }
    u32 rbase = (u32)t * 128u;
#pragma unroll
    for (int fc = 0; fc < 8; fc++) {
      float v0 = fmaxf(acc[fc][0] + bv[fc], 0.f);
      float v1 = fmaxf(acc[fc][1] + bv[fc], 0.f);
      float v2 = fmaxf(acc[fc][2] + bv[fc], 0.f);
      float v3 = fmaxf(acc[fc][3] + bv[fc], 0.f);
      s[fc] += (v0 + v1) + (v2 + v3);
      q[fc] += (v0*v0 + v1*v1) + (v2*v2 + v3*v3);
      float mx = fmaxf(fmaxf(v0, v1), fmaxf(v2, v3));
      float mn = fminf(fminf(v0, v1), fminf(v2, v3));
      mx = fmaxf(mx, __shfl_xor(mx, 16, 64)); mx = fmaxf(mx, __shfl_xor(mx, 32, 64));
      mn = fminf(mn, __shfl_xor(mn, 16, 64)); mn = fminf(mn, __shfl_xor(mn, 32, 64));
      if (l4 == (fc & 3))
        g_mm[rbase + fc*16 + l15] = (u32)f2bf(mx) | ((u32)f2bf(mn) << 16);
    }
  }
#pragma unroll
  for (int fc = 0; fc < 8; fc++) {
    float sv = s[fc], qv = q[fc];
    sv += __shfl_xor(sv, 16, 64); sv += __shfl_xor(sv, 32, 64);
    qv += __shfl_xor(qv, 16, 64); qv += __shfl_xor(qv, 32, 64);
    if (l4 == 0) { atomicAdd(&ssum[fc*16 + l15], sv); atomicAdd(&ssqs[fc*16 + l15], qv); }
  }
  __syncthreads();
  if (tid < 128) { atomicAdd(&g_sum[tid], ssum[tid]); atomicAdd(&g_sqs[tid], ssqs[tid]); }
}

// K3: agg = bn3-affine of packed max/min (sign-select); write f32 residual + bf16
__global__ void k3_agg() {
  int i4 = (blockIdx.x * 256 + threadIdx.x) * 4;
  if (i4 >= NM * 128) return;
  int c = i4 & 127;
  uint4 mm = *reinterpret_cast<const uint4*>(g_mm + i4);
  float4 a = *reinterpret_cast<const float4*>(g_cfa + c);
  float4 b = *reinterpret_cast<const float4*>(g_cfb + c);
  u32 u[4] = {mm.x, mm.y, mm.z, mm.w};
  float av[4] = {a.x, a.y, a.z, a.w};
  float bb[4] = {b.x, b.y, b.z, b.w};
  float4 r;
  float* rr = &r.x;
#pragma unroll
  for (int j = 0; j < 4; j++) {
    float mx = bf2f((u16)(u[j] & 0xFFFFu));
    float mn = bf2f((u16)(u[j] >> 16));
    rr[j] = av[j] > 0.f ? fmaf(av[j], mx, bb[j]) : fmaf(av[j], mn, bb[j]);
  }
  *reinterpret_cast<float4*>(g_agg + i4) = r;
  uint2 pk; pk.x = pack2(r.x, r.y); pk.y = pack2(r.z, r.w);
  *reinterpret_cast<uint2*>(g_aggbf + i4) = pk;
}

// ---------------- MFMA GEMM (proven: 2-buffer, __syncthreads, C-bounce) ------
template<int AID, int WID, int OID, int NPAN, bool OUT_BF16, bool BIAS_DEV>
__launch_bounds__(256, 4)
__global__ void gemm_mfma(const float* __restrict__ bias, int Mrows, int Kdim) {
  const int Ncols = NPAN * 128;
  const u16* __restrict__ A  = ubufsel<AID>();
  const u16* __restrict__ Bt = wsel<WID>();
  __shared__ u16 sLDS[16384];          // 32KB: A bufs [0..8191], B bufs [8192..]
  __shared__ float ssum[128], ssqs[128];
  u16* sA = sLDS;
  u16* sB = sLDS + 8192;
  const int tid = threadIdx.x;
  const int bid = blockIdx.x;
  const int m0 = (bid / NPAN) * 128, n0 = (bid % NPAN) * 128;
  if (tid < 128) { ssum[tid] = 0.f; ssqs[tid] = 0.f; }
  const int wave = tid >> 6, lane = tid & 63, l15 = lane & 15, l4 = lane >> 4;
  const int wr = wave >> 1, wc = wave & 1;
  const int ckk = (lane & 3) * 8;      // linear per-lane K offset (proven)
  f32x4 acc[4][4] = {};
  const int nt = Kdim >> 5;

  auto STAGE = [&](int buf, int t) {
    const int k0 = t * 32;
#pragma unroll
    for (int i = 0; i < 2; i++) {
      const int c = wave * 2 + i;
      int ar = m0 + c * 16 + (lane >> 2);
      if (ar >= Mrows) ar = Mrows - 1;               // clamp; results unused
      const int br = n0 + c * 16 + (lane >> 2);
      __builtin_amdgcn_global_load_lds(AS_GLOBAL(A  + (size_t)ar * Kdim + k0 + ckk),
                                       AS_LDS(sA + buf*4096 + c*512), 16, 0, 0);
      __builtin_amdgcn_global_load_lds(AS_GLOBAL(Bt + (size_t)br * Kdim + k0 + ckk),
                                       AS_LDS(sB + buf*4096 + c*512), 16, 0, 0);
    }
  };

  STAGE(0, 0);
  __syncthreads();                 // drains vmcnt -> buf0 ready
  int cur = 0;
  for (int t = 0; t < nt; ++t) {
    if (t + 1 < nt) STAGE(cur ^ 1, t + 1);   // issue next tile; hides under MFMA
    bf16x8 af[4], bf4[4];
#pragma unroll
    for (int fr = 0; fr < 4; fr++) {
      int r = wr*64 + fr*16 + l15;
      af[fr] = *reinterpret_cast<const bf16x8*>(sA + cur*4096 + r*32 + l4*8);
    }
#pragma unroll
    for (int fc = 0; fc < 4; fc++) {
      int r = wc*64 + fc*16 + l15;
      bf4[fc] = *reinterpret_cast<const bf16x8*>(sB + cur*4096 + r*32 + l4*8);
    }
#pragma unroll
    for (int fr = 0; fr < 4; fr++)
#pragma unroll
      for (int fc = 0; fc < 4; fc++)
        acc[fr][fc] = __builtin_amdgcn_mfma_f32_16x16x32_bf16(af[fr], bf4[fc], acc[fr][fc], 0, 0, 0);
    if (t + 1 < nt) { __syncthreads(); cur ^= 1; }
  }

  __syncthreads();   // all LDS reads done -> safe to reuse sLDS for C-bounce
  const int orow = m0 + wr*64 + l4*4;
#pragma unroll
  for (int fc = 0; fc < 4; fc++) {
    int col = n0 + wc*64 + fc*16 + l15;
    float bvv = BIAS_DEV ? g_pbadj[col] : bias[col];
    float s = 0.f, q = 0.f;
#pragma unroll
    for (int fr = 0; fr < 4; fr++)
#pragma unroll
      for (int r = 0; r < 4; r++) {
        int row = orow + fr*16 + r;
        if (row < Mrows) {
          float v = acc[fr][fc][r] + bvv;
          s += v; q += v*v;
          if (OUT_BF16) sLDS[(size_t)(wr*64 + fr*16 + l4*4 + r)*128 + wc*64 + fc*16 + l15] = f2bf(v);
          else          g_obuf[(size_t)row*Ncols + col] = v;
        }
      }
    atomicAdd(&ssum[wc*64 + fc*16 + l15], s);
    atomicAdd(&ssqs[wc*64 + fc*16 + l15], q);
  }
  __syncthreads();
  if (OUT_BF16) {
    // coalesced copy-out: thread -> 64 u16 (half a row, 128B) = 8 x uint4
    const int r2 = tid >> 1, hh = tid & 1;
    if (m0 + r2 < Mrows) {
      const uint4* src = reinterpret_cast<const uint4*>(sLDS + r2*128 + hh*64);
      uint4* dst = reinterpret_cast<uint4*>(obufsel<OID>() + (size_t)(m0 + r2)*Ncols + n0 + hh*64);
#pragma unroll
      for (int j = 0; j < 8; j++) dst[j] = src[j];
    }
  }
  if (tid < 128) { atomicAdd(&g_sum[n0 + tid], ssum[tid]); atomicAdd(&g_sqs[n0 + tid], ssqs[tid]); }
}

// ---------------- EW chain: y = chain of relu(a_i*x+b_i), banks 1..NCH ------
template<int INID, int OUTID, int NCH, bool WRITE, bool STATS>
__launch_bounds__(256)
__global__ void ew_chain(int rows) {
  const u16* __restrict__ X = ubufsel<INID>();
  u16* __restrict__ Y = obufsel<OUTID>();
  __shared__ float ssum[512], ssqs[512];
  const int tid = threadIdx.x;
  if (STATS) {
    ssum[tid] = 0.f; ssum[tid+256] = 0.f; ssqs[tid] = 0.f; ssqs[tid+256] = 0.f;
    __syncthreads();
  }
  const int c0 = (tid & 63) * 8;
  const int rl = tid >> 6;
  float a1[8], b1[8], a2[8], b2[8], a3[8], b3[8];
#pragma unroll
  for (int j = 0; j < 8; j++) {
    a1[j] = g_cfa[c0+j]; b1[j] = g_cfb[c0+j];
    if constexpr (NCH >= 2) { a2[j] = g_cfa2[c0+j]; b2[j] = g_cfb2[c0+j]; }
    if constexpr (NCH >= 3) { a3[j] = g_cfa3[c0+j]; b3[j] = g_cfb3[c0+j]; }
  }
  float s[8] = {}, q[8] = {};
  for (int r = blockIdx.x*4 + rl; r < rows; r += gridDim.x*4) {
    uint4 v = *reinterpret_cast<const uint4*>(X + (size_t)r*512 + c0);
    u32 u[4] = {v.x, v.y, v.z, v.w}, o[4];
#pragma unroll
    for (int t = 0; t < 4; t++) {
      float lo = bf2f((u16)(u[t] & 0xFFFFu));
      float hi = bf2f((u16)(u[t] >> 16));
      lo = fmaxf(fmaf(a1[2*t],   lo, b1[2*t]),   0.f);
      hi = fmaxf(fmaf(a1[2*t+1], hi, b1[2*t+1]), 0.f);
      if constexpr (NCH >= 2) {
        lo = fmaxf(fmaf(a2[2*t],   lo, b2[2*t]),   0.f);
        hi = fmaxf(fmaf(a2[2*t+1], hi, b2[2*t+1]), 0.f);
      }
      if constexpr (NCH >= 3) {
        lo = fmaxf(fmaf(a3[2*t],   lo, b3[2*t]),   0.f);
        hi = fmaxf(fmaf(a3[2*t+1], hi, b3[2*t+1]), 0.f);
      }
      if (STATS) { s[2*t] += lo; q[2*t] += lo*lo; s[2*t+1] += hi; q[2*t+1] += hi*hi; }
      if (WRITE) o[t] = (u32)f2bf(lo) | ((u32)f2bf(hi) << 16);
    }
    if (WRITE) *reinterpret_cast<uint4*>(Y + (size_t)r*512 + c0) = make_uint4(o[0], o[1], o[2], o[3]);
  }
  if (STATS) {
#pragma unroll
    for (int j = 0; j < 8; j++) { atomicAdd(&ssum[c0+j], s[j]); atomicAdd(&ssqs[c0+j], q[j]); }
    __syncthreads();
    atomicAdd(&g_sum[tid],     ssum[tid]);     atomicAdd(&g_sqs[tid],     ssqs[tid]);
    atomicAdd(&g_sum[tid+256], ssum[tid+256]); atomicAdd(&g_sqs[tid+256], ssqs[tid+256]);
  }
}

__global__ void final_out(float* __restrict__ out) {
  int i4 = (blockIdx.x * 256 + threadIdx.x) * 4;
  if (i4 >= NM * 128) return;
  int c = i4 & 127;
  float4 o  = *reinterpret_cast<const float4*>(g_obuf + i4);
  float4 ag = *reinterpret_cast<const float4*>(g_agg + i4);
  float4 a  = *reinterpret_cast<const float4*>(g_cfa + c);
  float4 b  = *reinterpret_cast<const float4*>(g_cfb + c);
  float4 r;
  r.x = fmaxf(fmaf(a.x, o.x, b.x) + ag.x, 0.f);
  r.y = fmaxf(fmaf(a.y, o.y, b.y) + ag.y, 0.f);
  r.z = fmaxf(fmaf(a.z, o.z, b.z) + ag.z, 0.f);
  r.w = fmaxf(fmaf(a.w, o.w, b.w) + ag.w, 0.f);
  *reinterpret_cast<float4*>(out + i4) = r;
}

// ---------------- host launch ------------------------------------------------
extern "C" void kernel_launch(void* const* d_in, const int* in_sizes, int n_in,
                              void* d_out, int out_size, void* d_ws, size_t ws_size,
                              hipStream_t stream) {
  const float* x     = (const float*)d_in[0];
  const float* pos   = (const float*)d_in[1];
  const int*   batch = (const int*)  d_in[2];
  const float* refl  = (const float*)d_in[3];
  const float* sf    = (const float*)d_in[4];
  const int*   idx   = (const int*)  d_in[5];
  const int*   esrc  = (const int*)  d_in[6];
  const float* W1  = (const float*)d_in[8];
  const float* b1  = (const float*)d_in[9];
  const float* W2  = (const float*)d_in[10];
  const float* b2  = (const float*)d_in[11];
  const float* g2  = (const float*)d_in[12];
  const float* be2 = (const float*)d_in[13];
  const float* W3  = (const float*)d_in[14];
  const float* b3  = (const float*)d_in[15];
  const float* g3  = (const float*)d_in[16];
  const float* be3 = (const float*)d_in[17];
  const float* expW  = (const float*)d_in[24];
  const float* expb  = (const float*)d_in[25];
  const float* expg  = (const float*)d_in[26];
  const float* expbe = (const float*)d_in[27];
  const float* dww  = (const float*)d_in[28];
  const float* dwg  = (const float*)d_in[30];
  const float* dwbe = (const float*)d_in[31];
  const float* pwW  = (const float*)d_in[32];
  const float* pwb  = (const float*)d_in[33];
  const float* pwg  = (const float*)d_in[34];
  const float* pwbe = (const float*)d_in[35];
  const float* cg   = (const float*)d_in[36];
  const float* cbe  = (const float*)d_in[37];
  const float* projW  = (const float*)d_in[38];
  const float* projb  = (const float*)d_in[39];
  const float* projg  = (const float*)d_in[40];
  const float* projbe = (const float*)d_in[41];
  float* out = (float*)d_out;

  const float fNE = (float)NE, fNM = (float)NM;

  prep_weights<<<2624, 256, 0, stream>>>(W1, W2, W3, expW, pwW, projW);
  prep_pos_x<<<(NP + 255)/256, 256, 0, stream>>>(pos, batch, refl, sf, x);
  tail_out<<<(NM + 255)/256, 256, 0, stream>>>(pos, batch, refl, sf, idx, out);
  zero_stats<<<1, 512, 0, stream>>>();

  k1_edge<<<K1_BLOCKS, 256, 0, stream>>>(esrc, idx, b1, b2);          // stats(pre2)
  param_bn<1><<<1, 512, 0, stream>>>(g2, be2, fNE, 64);
  scale_fold<0><<<32, 256, 0, stream>>>(b3, 128, 64);                 // fold bn2 into W3/b3
  k2_edge<<<K2_BLOCKS, 256, 0, stream>>>();                           // stats(pre3) + max/min
  param_bn<1><<<1, 512, 0, stream>>>(g3, be3, fNE, 128);
  k3_agg<<<NM*128/1024, 256, 0, stream>>>();

  // t1 = agg @ expW + expb   (stats(t1))
  gemm_mfma<1, 3, 2, 4, true, false><<<469*4, 256, 0, stream>>>(expb, NM, 128);
  param_bn<1><<<1, 512, 0, stream>>>(expg, expbe, fNM, 512);          // bn_exp -> bank1
  ew_chain<2, 3, 1, false, true><<<1024, 256, 0, stream>>>(NM);       // stats(e), no write
  param_dw<2><<<1, 512, 0, stream>>>(dww, dwg, dwbe, fNM, 512);       // dw0 -> bank2
  ew_chain<2, 3, 2, true, false><<<1024, 256, 0, stream>>>(NM);       // z0 -> bufB
  // p0 = z0 @ pw0 + pwb0   (stats(p0))
  gemm_mfma<3, 4, 2, 4, true, false><<<469*4, 256, 0, stream>>>(pwb, NM, 512);
  param_bn<1><<<1, 512, 0, stream>>>(pwg, pwbe, fNM, 512);            // bn_pw0 -> bank1
  ew_chain<2, 3, 1, false, true><<<1024, 256, 0, stream>>>(NM);       // stats(v0)
  param_bn<2><<<1, 512, 0, stream>>>(cg, cbe, fNM, 512);              // bn_c0 -> bank2
  ew_chain<2, 3, 2, false, true><<<1024, 256, 0, stream>>>(NM);       // stats(cmid)
  param_dw<3><<<1, 512, 0, stream>>>(dww + 512, dwg + 512, dwbe + 512, fNM, 512); // dw1 -> bank3
  ew_chain<2, 3, 3, true, false><<<1024, 256, 0, stream>>>(NM);       // z1 -> bufB
  // p1 = z1 @ pw1 + pwb1   (stats(p1))
  gemm_mfma<3, 5, 2, 4, true, false><<<469*4, 256, 0, stream>>>(pwb + 512, NM, 512);
  param_bn<1><<<1, 512, 0, stream>>>(pwg + 512, pwbe + 512, fNM, 512);// bn_pw1 -> bank1
  ew_chain<2, 2, 1, true, true><<<1024, 256, 0, stream>>>(NM);        // v1 -> bufA (in place), stats(v1)
  param_bn<1><<<1, 512, 0, stream>>>(cg + 512, cbe + 512, fNM, 512);  // bn_c1 -> bank1
  scale_fold<1><<<32, 256, 0, stream>>>(projb, 128, 512);             // fold c1-bn into projW/projb
  // o = v1 @ projW' + pbadj  (f32 out, N=128)
  gemm_mfma<2, 6, 0, 1, false, true><<<469, 256, 0, stream>>>(projb, NM, 512);
  param_bn<1><<<1, 512, 0, stream>>>(projg, projbe, fNM, 128);
  final_out<<<NM*128/1024, 256, 0, stream>>>(out);
}